// Round 1
// baseline (3127.133 us; speedup 1.0000x reference)
//
#include <hip/hip_runtime.h>
#include <math.h>

constexpr int B  = 8;
constexpr int C  = 256;
constexpr int L  = 16384;
constexpr int CH = 64;    // c = C/4
constexpr int NB = 256;   // L / BL
// BL = 64, window = 128

// ---------------------------------------------------------------------------
// Kernel 1: q/k/v projections.  grid (L/64, B, 3), block 256.
// z=0: q = Wq@x1+bq, z=1: k = Wk@x1+bk, z=2: v = Wv@x2+bv
// lanes = positions (coalesced); W via wave-uniform scalar loads.
// ---------------------------------------------------------------------------
__global__ __launch_bounds__(256) void qkv_kernel(
    const float* __restrict__ x1, const float* __restrict__ x2,
    const float* __restrict__ Wq, const float* __restrict__ bq,
    const float* __restrict__ Wk, const float* __restrict__ bk,
    const float* __restrict__ Wv, const float* __restrict__ bv,
    float* __restrict__ qkv_ws)
{
    const int t = threadIdx.x;
    const int l = t & 63;
    const int g = __builtin_amdgcn_readfirstlane(t >> 6);  // 0..3, wave-uniform
    const int tile = blockIdx.x;
    const int b = blockIdx.y;
    const int z = blockIdx.z;

    const float* x    = (z == 2) ? x2 : x1;
    const float* W    = (z == 0) ? Wq : (z == 1 ? Wk : Wv);
    const float* bias = (z == 0) ? bq : (z == 1 ? bk : bv);
    float* out = qkv_ws + (size_t)z * B * CH * L;

    const int pos = tile * 64 + l;
    const float* xp = x + (size_t)b * C * L + pos;
    const float* Wg = W + g * 16 * C;

    float acc[16];
#pragma unroll
    for (int m = 0; m < 16; ++m) acc[m] = 0.f;

#pragma unroll 4
    for (int c = 0; c < C; ++c) {
        float xv = xp[(size_t)c * L];
#pragma unroll
        for (int m = 0; m < 16; ++m)
            acc[m] += Wg[m * C + c] * xv;   // scalar (SGPR) W operand
    }
#pragma unroll
    for (int m = 0; m < 16; ++m) {
        int och = g * 16 + m;
        out[((size_t)b * CH + och) * L + pos] = acc[m] + bias[och];
    }
}

// ---------------------------------------------------------------------------
// Kernel 2: windowed attention + fused ReLU + Wo projection + final mask.
// grid 2048 blocks: i = n*8 + b  (kw/output ordering).
// q block comes from the SCRAMBLED index: b' = i>>8, n' = i&255 (q_blk order).
// LDS (64 KB dynamic): region0 [64][128] k -> att_t [128][64]
//                      region1 [64][128] v -> attout [64][64]
// ---------------------------------------------------------------------------
__global__ __launch_bounds__(256) void attn_kernel(
    const float* __restrict__ qws, const float* __restrict__ kws,
    const float* __restrict__ vws, const float* __restrict__ mask,
    const float* __restrict__ Wo,  const float* __restrict__ bo,
    float* __restrict__ outp)
{
    extern __shared__ float lds[];
    float* ldsK = lds;          // 8192 floats
    float* ldsV = lds + 8192;   // 8192 floats

    const int i  = blockIdx.x;
    const int b  = i & 7;       // kv / mask / output batch
    const int n  = i >> 3;      // kv / mask / output block
    const int bqi = i >> 8;     // q batch  (scrambled pairing)
    const int nqi = i & 255;    // q block
    const int t  = threadIdx.x;

    // ---- stage k,v windows: c in [0,64), j in [0,128), pos = n*64-64+j ----
    {
        const float* kbase = kws + (size_t)b * CH * L + n * 64 - 64;
        const float* vbase = vws + (size_t)b * CH * L + n * 64 - 64;
#pragma unroll
        for (int it = 0; it < 8; ++it) {
            int f  = t + it * 256;       // 0..2047
            int c  = f >> 5;
            int j4 = (f & 31) * 4;
            float4 kv, vv;
            if (n == 0 && j4 < 64) {
                kv = make_float4(0.f, 0.f, 0.f, 0.f); vv = kv;
            } else {
                kv = *(const float4*)(kbase + (size_t)c * L + j4);
                vv = *(const float4*)(vbase + (size_t)c * L + j4);
            }
            *(float4*)(ldsK + c * 128 + j4) = kv;
            *(float4*)(ldsV + c * 128 + j4) = vv;
        }
    }

    const int l  = t >> 2;   // query row 0..63
    const int jg = t & 3;    // j-group: j = jg*4 + jj*16 + r

    // ---- q into registers: q_r[c] = q[bqi][c][nqi*64 + l] ----
    float q_r[64];
    {
        const float* qbase = qws + (size_t)bqi * CH * L + nqi * 64 + l;
#pragma unroll
        for (int c = 0; c < 64; ++c) q_r[c] = qbase[(size_t)c * L];
    }
    __syncthreads();

    // ---- energy ----
    float e[32];
#pragma unroll
    for (int x = 0; x < 32; ++x) e[x] = 0.f;
#pragma unroll
    for (int c = 0; c < 64; ++c) {
        float qv = q_r[c];
#pragma unroll
        for (int jj = 0; jj < 8; ++jj) {
            float4 kv = *(const float4*)(ldsK + c * 128 + jg * 4 + jj * 16);
            e[jj * 4 + 0] += qv * kv.x;
            e[jj * 4 + 1] += qv * kv.y;
            e[jj * 4 + 2] += qv * kv.z;
            e[jj * 4 + 3] += qv * kv.w;
        }
    }

    // ---- mask + softmax (jax: softmax(e/8 + log(fm+1e-6)) * fm) ----
    const float* maskw = mask + (size_t)b * L + n * 64 - 64;
    float fm[32];
#pragma unroll
    for (int jj = 0; jj < 8; ++jj) {
#pragma unroll
        for (int r = 0; r < 4; ++r) {
            int j = jg * 4 + jj * 16 + r;
            float pw = (n == 0 && j < 64) ? 0.f : maskw[j];
            float w  = (j >= l && j < l + 64) ? 1.f : 0.f;
            float f  = w * pw;
            fm[jj * 4 + r] = f;
            e[jj * 4 + r] = e[jj * 4 + r] * 0.125f + logf(f + 1e-6f);
        }
    }
    float mx = -INFINITY;
#pragma unroll
    for (int x = 0; x < 32; ++x) mx = fmaxf(mx, e[x]);
    mx = fmaxf(mx, __shfl_xor(mx, 1));
    mx = fmaxf(mx, __shfl_xor(mx, 2));
    float sum = 0.f;
#pragma unroll
    for (int x = 0; x < 32; ++x) { e[x] = expf(e[x] - mx); sum += e[x]; }
    sum += __shfl_xor(sum, 1);
    sum += __shfl_xor(sum, 2);
    const float inv = 1.0f / sum;

    __syncthreads();   // everyone done reading k before att_t overwrites it
#pragma unroll
    for (int jj = 0; jj < 8; ++jj)
#pragma unroll
        for (int r = 0; r < 4; ++r) {
            int j = jg * 4 + jj * 16 + r;
            ldsK[j * 64 + l] = e[jj * 4 + r] * inv * fm[jj * 4 + r]; // att_t[j][l]
        }
    __syncthreads();

    // ---- attout[c][l] = sum_j v[c][j] * att[l][j] ----
    const int l3 = t & 63;
    const int cg = t >> 6;
    float acc[16];
#pragma unroll
    for (int m = 0; m < 16; ++m) acc[m] = 0.f;
#pragma unroll 2
    for (int j = 0; j < 128; j += 4) {
        float a0 = ldsK[(j + 0) * 64 + l3];
        float a1 = ldsK[(j + 1) * 64 + l3];
        float a2 = ldsK[(j + 2) * 64 + l3];
        float a3 = ldsK[(j + 3) * 64 + l3];
#pragma unroll
        for (int m = 0; m < 16; ++m) {
            float4 v4 = *(const float4*)(ldsV + (cg * 16 + m) * 128 + j);
            acc[m] += v4.x * a0 + v4.y * a1 + v4.z * a2 + v4.w * a3;
        }
    }
    __syncthreads();   // all v reads done
#pragma unroll
    for (int m = 0; m < 16; ++m)
        ldsV[(cg * 16 + m) * 64 + l3] = fmaxf(acc[m], 0.f);  // relu(attout)
    __syncthreads();

    // ---- final: out[o][pos] = (Wo @ relu(attout) + bo) * mask ----
    const int l4 = t & 63;
    const int og = __builtin_amdgcn_readfirstlane(t >> 6);
    float attr[64];
#pragma unroll
    for (int c = 0; c < 64; ++c) attr[c] = ldsV[c * 64 + l4];

    const int pos = n * 64 + l4;
    const float mv = mask[(size_t)b * L + pos];
    float* outb = outp + (size_t)b * C * L + pos;
    const float* Wor = Wo + og * 64 * 64;   // Wo is (256 x 64) row-major
#pragma unroll 1
    for (int oo = 0; oo < 64; ++oo) {
        float a = bo[og * 64 + oo];
#pragma unroll
        for (int c = 0; c < 64; ++c)
            a += Wor[oo * 64 + c] * attr[c];   // scalar (SGPR) Wo operand
        outb[(size_t)(og * 64 + oo) * L] = a * mv;
    }
}

// ---------------------------------------------------------------------------
extern "C" void kernel_launch(void* const* d_in, const int* in_sizes, int n_in,
                              void* d_out, int out_size, void* d_ws, size_t ws_size,
                              hipStream_t stream) {
    const float* x1   = (const float*)d_in[0];
    const float* x2   = (const float*)d_in[1];
    const float* mask = (const float*)d_in[2];
    const float* Wq   = (const float*)d_in[3];
    const float* bq   = (const float*)d_in[4];
    const float* Wk   = (const float*)d_in[5];
    const float* bk   = (const float*)d_in[6];
    const float* Wv   = (const float*)d_in[7];
    const float* bv   = (const float*)d_in[8];
    const float* Wo   = (const float*)d_in[9];
    const float* bo   = (const float*)d_in[10];
    float* out = (float*)d_out;
    float* ws  = (float*)d_ws;

    const size_t plane = (size_t)B * CH * L;          // 8*64*16384 floats
    const size_t need  = 3 * plane * sizeof(float);   // 96 MiB
    if (ws_size < need) {
        // ws too small: emit zeros so the failure mode is recognizable
        hipMemsetAsync(d_out, 0, (size_t)out_size * sizeof(float), stream);
        return;
    }

    dim3 g1(L / 64, B, 3);
    qkv_kernel<<<g1, 256, 0, stream>>>(x1, x2, Wq, bq, Wk, bk, Wv, bv, ws);

    attn_kernel<<<dim3(NB * B), 256, 65536, stream>>>(
        ws, ws + plane, ws + 2 * plane, mask, Wo, bo, out);
}

// Round 2
// 505.874 us; speedup vs baseline: 6.1816x; 6.1816x over previous
//
#include <hip/hip_runtime.h>
#include <math.h>

constexpr int B  = 8;
constexpr int C  = 256;
constexpr int L  = 16384;
constexpr int CH = 64;    // c = C/4
constexpr int NB = 256;   // L / BL
// BL = 64, window = 128

// ---------------------------------------------------------------------------
// Kernel 1: q/k/v projections.  grid (L/64, B, 3), block 256.
// ---------------------------------------------------------------------------
__global__ __launch_bounds__(256) void qkv_kernel(
    const float* __restrict__ x1, const float* __restrict__ x2,
    const float* __restrict__ Wq, const float* __restrict__ bq,
    const float* __restrict__ Wk, const float* __restrict__ bk,
    const float* __restrict__ Wv, const float* __restrict__ bv,
    float* __restrict__ qkv_ws)
{
    const int t = threadIdx.x;
    const int l = t & 63;
    const int g = __builtin_amdgcn_readfirstlane(t >> 6);  // 0..3, wave-uniform
    const int tile = blockIdx.x;
    const int b = blockIdx.y;
    const int z = blockIdx.z;

    const float* x    = (z == 2) ? x2 : x1;
    const float* W    = (z == 0) ? Wq : (z == 1 ? Wk : Wv);
    const float* bias = (z == 0) ? bq : (z == 1 ? bk : bv);
    float* out = qkv_ws + (size_t)z * B * CH * L;

    const int pos = tile * 64 + l;
    const float* xp = x + (size_t)b * C * L + pos;
    const float* Wg = W + g * 16 * C;

    float acc[16];
#pragma unroll
    for (int m = 0; m < 16; ++m) acc[m] = 0.f;

#pragma unroll 4
    for (int c = 0; c < C; ++c) {
        float xv = xp[(size_t)c * L];
#pragma unroll
        for (int m = 0; m < 16; ++m)
            acc[m] += Wg[m * C + c] * xv;   // scalar (SGPR) W operand
    }
#pragma unroll
    for (int m = 0; m < 16; ++m) {
        int och = g * 16 + m;
        out[((size_t)b * CH + och) * L + pos] = acc[m] + bias[och];
    }
}

// ---------------------------------------------------------------------------
// Kernel 2: windowed attention + fused ReLU + Wo projection + final mask.
// grid 2048 blocks: i = n*8 + b (kw/output order); q from scrambled (i>>8,i&255).
// LDS 80 KB: ldsK [64][128] (32K) -> att_t [128][64]
//            ldsV [64][128] (32K)
//            ldsQ [64][64]  (16K) -> relu(attout) [64][64]
// No per-thread array > 32 elems => no scratch spills.
// ---------------------------------------------------------------------------
__global__ __launch_bounds__(256) void attn_kernel(
    const float* __restrict__ qws, const float* __restrict__ kws,
    const float* __restrict__ vws, const float* __restrict__ mask,
    const float* __restrict__ Wo,  const float* __restrict__ bo,
    float* __restrict__ outp)
{
    extern __shared__ float lds[];
    float* ldsK = lds;           // 8192 floats
    float* ldsV = lds + 8192;    // 8192 floats
    float* ldsQ = lds + 16384;   // 4096 floats

    const int i  = blockIdx.x;
    const int b  = i & 7;       // kv / mask / output batch
    const int n  = i >> 3;      // kv / mask / output block
    const int bqi = i >> 8;     // q batch  (scrambled pairing)
    const int nqi = i & 255;    // q block
    const int t  = threadIdx.x;

    // ---- stage k,v windows: c in [0,64), j in [0,128), pos = n*64-64+j ----
    {
        const float* kbase = kws + (size_t)b * CH * L + n * 64 - 64;
        const float* vbase = vws + (size_t)b * CH * L + n * 64 - 64;
#pragma unroll
        for (int it = 0; it < 8; ++it) {
            int f  = t + it * 256;       // 0..2047
            int c  = f >> 5;
            int j4 = (f & 31) * 4;
            float4 kv, vv;
            if (n == 0 && j4 < 64) {
                kv = make_float4(0.f, 0.f, 0.f, 0.f); vv = kv;
            } else {
                kv = *(const float4*)(kbase + (size_t)c * L + j4);
                vv = *(const float4*)(vbase + (size_t)c * L + j4);
            }
            *(float4*)(ldsK + c * 128 + j4) = kv;
            *(float4*)(ldsV + c * 128 + j4) = vv;
        }
    }
    // ---- stage q tile: ldsQ[c][l] = q[bqi][c][nqi*64 + l] ----
    {
        const float* qbase = qws + (size_t)bqi * CH * L + nqi * 64;
#pragma unroll
        for (int it = 0; it < 4; ++it) {
            int f  = t + it * 256;       // 0..1023
            int c  = f >> 4;
            int l4 = (f & 15) * 4;
            float4 qv = *(const float4*)(qbase + (size_t)c * L + l4);
            *(float4*)(ldsQ + c * 64 + l4) = qv;
        }
    }
    __syncthreads();

    const int l  = t >> 2;   // query row 0..63
    const int jg = t & 3;    // j-group: j = jg*4 + jj*16 + r

    // ---- energy: e[l][j] = sum_c q[c][l] * k[c][j] ----
    float e[32];
#pragma unroll
    for (int x = 0; x < 32; ++x) e[x] = 0.f;
#pragma unroll 8
    for (int c = 0; c < 64; ++c) {
        const float qv = ldsQ[c * 64 + l];
        const float* kr = ldsK + c * 128 + jg * 4;
#pragma unroll
        for (int jj = 0; jj < 8; ++jj) {
            float4 kv = *(const float4*)(kr + jj * 16);
            e[jj * 4 + 0] = fmaf(qv, kv.x, e[jj * 4 + 0]);
            e[jj * 4 + 1] = fmaf(qv, kv.y, e[jj * 4 + 1]);
            e[jj * 4 + 2] = fmaf(qv, kv.z, e[jj * 4 + 2]);
            e[jj * 4 + 3] = fmaf(qv, kv.w, e[jj * 4 + 3]);
        }
    }

    // ---- mask + softmax (jax: softmax(e/8 + log(fm+1e-6)) * fm) ----
    const float* maskw = mask + (size_t)b * L + n * 64 - 64;
    float fm[32];
#pragma unroll
    for (int jj = 0; jj < 8; ++jj) {
        const int jbase = jg * 4 + jj * 16;
        float4 pw4;
        if (n == 0 && jbase < 64) pw4 = make_float4(0.f, 0.f, 0.f, 0.f);
        else                      pw4 = *(const float4*)(maskw + jbase);
#pragma unroll
        for (int r = 0; r < 4; ++r) {
            int j = jbase + r;
            float pw = (r == 0) ? pw4.x : (r == 1) ? pw4.y : (r == 2) ? pw4.z : pw4.w;
            float w  = (j >= l && j < l + 64) ? 1.f : 0.f;
            float f  = w * pw;
            fm[jj * 4 + r] = f;
            e[jj * 4 + r] = e[jj * 4 + r] * 0.125f + __logf(f + 1e-6f);
        }
    }
    float mx = -INFINITY;
#pragma unroll
    for (int x = 0; x < 32; ++x) mx = fmaxf(mx, e[x]);
    mx = fmaxf(mx, __shfl_xor(mx, 1));
    mx = fmaxf(mx, __shfl_xor(mx, 2));
    float sum = 0.f;
#pragma unroll
    for (int x = 0; x < 32; ++x) { e[x] = __expf(e[x] - mx); sum += e[x]; }
    sum += __shfl_xor(sum, 1);
    sum += __shfl_xor(sum, 2);
    const float inv = 1.0f / sum;

    __syncthreads();   // everyone done reading k before att_t overwrites it
#pragma unroll
    for (int jj = 0; jj < 8; ++jj)
#pragma unroll
        for (int r = 0; r < 4; ++r) {
            int j = jg * 4 + jj * 16 + r;
            ldsK[j * 64 + l] = e[jj * 4 + r] * inv * fm[jj * 4 + r]; // att_t[j][l]
        }
    __syncthreads();

    // ---- attout[c][l] = sum_j v[c][j] * att[l][j];  relu -> ldsQ ----
    const int l3 = t & 63;
    const int cg = t >> 6;
    {
        float acc[16];
#pragma unroll
        for (int m = 0; m < 16; ++m) acc[m] = 0.f;
#pragma unroll 2
        for (int j = 0; j < 128; j += 4) {
            float a0 = ldsK[(j + 0) * 64 + l3];
            float a1 = ldsK[(j + 1) * 64 + l3];
            float a2 = ldsK[(j + 2) * 64 + l3];
            float a3 = ldsK[(j + 3) * 64 + l3];
#pragma unroll
            for (int m = 0; m < 16; ++m) {
                float4 v4 = *(const float4*)(ldsV + (cg * 16 + m) * 128 + j);
                acc[m] = fmaf(v4.x, a0, acc[m]);
                acc[m] = fmaf(v4.y, a1, acc[m]);
                acc[m] = fmaf(v4.z, a2, acc[m]);
                acc[m] = fmaf(v4.w, a3, acc[m]);
            }
        }
        __syncthreads();   // q reads long done; ldsQ reusable
#pragma unroll
        for (int m = 0; m < 16; ++m)
            ldsQ[(cg * 16 + m) * 64 + l3] = fmaxf(acc[m], 0.f);
    }
    __syncthreads();

    // ---- final: out[o][pos] = (Wo @ relu(attout) + bo) * mask ----
    // 4 chunks of 16 output channels; acc[16] only, scalar Wo operands.
    const int l4 = t & 63;
    const int og = __builtin_amdgcn_readfirstlane(t >> 6);
    const int pos = n * 64 + l4;
    const float mv = mask[(size_t)b * L + pos];
    float* outb = outp + (size_t)b * C * L + pos;

#pragma unroll 1
    for (int chunk = 0; chunk < 4; ++chunk) {
        const int obase = og * 64 + chunk * 16;
        float acc2[16];
#pragma unroll
        for (int m = 0; m < 16; ++m) acc2[m] = bo[obase + m];
#pragma unroll 4
        for (int c = 0; c < 64; ++c) {
            float av = ldsQ[c * 64 + l4];
#pragma unroll
            for (int m = 0; m < 16; ++m)
                acc2[m] = fmaf(Wo[(size_t)(obase + m) * 64 + c], av, acc2[m]);
        }
#pragma unroll
        for (int m = 0; m < 16; ++m)
            outb[(size_t)(obase + m) * L] = acc2[m] * mv;
    }
}

// ---------------------------------------------------------------------------
extern "C" void kernel_launch(void* const* d_in, const int* in_sizes, int n_in,
                              void* d_out, int out_size, void* d_ws, size_t ws_size,
                              hipStream_t stream) {
    const float* x1   = (const float*)d_in[0];
    const float* x2   = (const float*)d_in[1];
    const float* mask = (const float*)d_in[2];
    const float* Wq   = (const float*)d_in[3];
    const float* bq   = (const float*)d_in[4];
    const float* Wk   = (const float*)d_in[5];
    const float* bk   = (const float*)d_in[6];
    const float* Wv   = (const float*)d_in[7];
    const float* bv   = (const float*)d_in[8];
    const float* Wo   = (const float*)d_in[9];
    const float* bo   = (const float*)d_in[10];
    float* out = (float*)d_out;
    float* ws  = (float*)d_ws;

    const size_t plane = (size_t)B * CH * L;          // 8*64*16384 floats
    const size_t need  = 3 * plane * sizeof(float);   // 96 MiB
    if (ws_size < need) {
        hipMemsetAsync(d_out, 0, (size_t)out_size * sizeof(float), stream);
        return;
    }

    dim3 g1(L / 64, B, 3);
    qkv_kernel<<<g1, 256, 0, stream>>>(x1, x2, Wq, bq, Wk, bk, Wv, bv, ws);

    attn_kernel<<<dim3(NB * B), 256, 81920, stream>>>(
        ws, ws + plane, ws + 2 * plane, mask, Wo, bo, out);
}

// Round 3
// 175.229 us; speedup vs baseline: 17.8460x; 2.8869x over previous
//
#include <hip/hip_runtime.h>
#include <math.h>

constexpr int B  = 8;
constexpr int C  = 256;
constexpr int L  = 16384;
constexpr int CH = 64;    // c = C/4
constexpr int NB = 256;   // L / BL

typedef __attribute__((ext_vector_type(8))) short bf16x8;
typedef __attribute__((ext_vector_type(4))) float f32x4;

__device__ __forceinline__ unsigned short f2bf(float f) {
    unsigned u = __builtin_bit_cast(unsigned, f);
    u += 0x7fffu + ((u >> 16) & 1u);          // round-to-nearest-even
    return (unsigned short)(u >> 16);
}

__device__ __forceinline__ f32x4 mfma16(bf16x8 a, bf16x8 b, f32x4 c) {
    return __builtin_amdgcn_mfma_f32_16x16x32_bf16(a, b, c, 0, 0, 0);
}

__device__ __forceinline__ bf16x8 pack8(const float* __restrict__ p) {
    float4 f0 = *(const float4*)p;
    float4 f1 = *(const float4*)(p + 4);
    bf16x8 r;
    r[0] = (short)f2bf(f0.x); r[1] = (short)f2bf(f0.y);
    r[2] = (short)f2bf(f0.z); r[3] = (short)f2bf(f0.w);
    r[4] = (short)f2bf(f1.x); r[5] = (short)f2bf(f1.y);
    r[6] = (short)f2bf(f1.z); r[7] = (short)f2bf(f1.w);
    return r;
}

// ---------------------------------------------------------------------------
// Kernel 1: q/k/v projections via MFMA.  grid (L/64, B), block 256 (4 waves).
// A = W stripe (wave w: och w*16..w*16+15), held as register fragments.
// B = x tile staged in LDS as [pos][c] bf16, quad^(pos&7) swizzled.
// Outputs: q,k transposed [b][pos][och] bf16;  v natural [b][och][pos] bf16.
// ---------------------------------------------------------------------------
__global__ __launch_bounds__(256) void qkv_mfma(
    const float* __restrict__ x1, const float* __restrict__ x2,
    const float* __restrict__ Wq, const float* __restrict__ bq,
    const float* __restrict__ Wk, const float* __restrict__ bk,
    const float* __restrict__ Wv, const float* __restrict__ bv,
    unsigned short* __restrict__ qt, unsigned short* __restrict__ kt,
    unsigned short* __restrict__ vt)
{
    __shared__ unsigned short xs[2][64 * 256];   // 2 x 32KB, [pos][c] swizzled
    const int t    = threadIdx.x;
    const int b    = blockIdx.y;
    const int pos0 = blockIdx.x * 64;
    const int lane = t & 63;
    const int w    = t >> 6;
    const int g    = lane >> 4;
    const int l15  = lane & 15;

    // ---- A fragments (W rows) + biases ----
    const int arow = w * 16 + l15;
    bf16x8 aq[8], ak[8], av[8];
#pragma unroll
    for (int s = 0; s < 8; ++s) {
        const int cb = s * 32 + g * 8;
        aq[s] = pack8(Wq + arow * 256 + cb);
        ak[s] = pack8(Wk + arow * 256 + cb);
        av[s] = pack8(Wv + arow * 256 + cb);
    }
    const f32x4 bq4 = *(const f32x4*)(bq + w * 16 + g * 4);
    const f32x4 bk4 = *(const f32x4*)(bk + w * 16 + g * 4);
    const f32x4 bv4 = *(const f32x4*)(bv + w * 16 + g * 4);

    // ---- stage x1, x2: fp32 [c][pos] -> bf16 LDS [pos][c] swizzled ----
    {
        const int p2  = (t & 31) * 2;   // pos pair
        const int cp0 = t >> 5;         // c-pair 0..7 (+8/iter)
#pragma unroll
        for (int xi = 0; xi < 2; ++xi) {
            const float* xb = (xi ? x2 : x1) + (size_t)b * C * L + pos0;
            char* dst = (char*)xs[xi];
#pragma unroll
            for (int it = 0; it < 16; ++it) {
                const int cp = cp0 + it * 8;
                const int c0 = cp * 2;
                const float2 fa = *(const float2*)(xb + (size_t)c0 * L + p2);
                const float2 fb = *(const float2*)(xb + (size_t)(c0 + 1) * L + p2);
                const unsigned w0 = (unsigned)f2bf(fa.x) | ((unsigned)f2bf(fb.x) << 16);
                const unsigned w1 = (unsigned)f2bf(fa.y) | ((unsigned)f2bf(fb.y) << 16);
                const int quad = cp >> 2, inner = (cp & 3) * 4;
                *(unsigned*)(dst + p2 * 512 + ((quad ^ (p2 & 7)) << 4) + inner) = w0;
                *(unsigned*)(dst + (p2 + 1) * 512 + ((quad ^ ((p2 + 1) & 7)) << 4) + inner) = w1;
            }
        }
    }
    __syncthreads();

    // ---- MFMA over 4 pos sub-tiles ----
#pragma unroll 1
    for (int nt = 0; nt < 4; ++nt) {
        f32x4 accq = {0.f, 0.f, 0.f, 0.f}, acck = accq, accv = accq;
        const int prow = nt * 16 + l15;
        const int rswz = prow & 7;
#pragma unroll
        for (int s = 0; s < 8; ++s) {
            const int byo = prow * 512 + (((s * 4 + g) ^ rswz) << 4);
            const bf16x8 bx1 = *(const bf16x8*)((char*)xs[0] + byo);
            const bf16x8 bx2 = *(const bf16x8*)((char*)xs[1] + byo);
            accq = mfma16(aq[s], bx1, accq);
            acck = mfma16(ak[s], bx1, acck);
            accv = mfma16(av[s], bx2, accv);
        }
        const int pos = pos0 + nt * 16 + l15;
        // q, k transposed: [b][pos][och], 4 consecutive och per lane -> 8B store
        {
            uint2 val;
            val.x = (unsigned)f2bf(accq[0] + bq4[0]) | ((unsigned)f2bf(accq[1] + bq4[1]) << 16);
            val.y = (unsigned)f2bf(accq[2] + bq4[2]) | ((unsigned)f2bf(accq[3] + bq4[3]) << 16);
            *(uint2*)(qt + ((size_t)b * L + pos) * 64 + w * 16 + g * 4) = val;
        }
        {
            uint2 val;
            val.x = (unsigned)f2bf(acck[0] + bk4[0]) | ((unsigned)f2bf(acck[1] + bk4[1]) << 16);
            val.y = (unsigned)f2bf(acck[2] + bk4[2]) | ((unsigned)f2bf(acck[3] + bk4[3]) << 16);
            *(uint2*)(kt + ((size_t)b * L + pos) * 64 + w * 16 + g * 4) = val;
        }
        // v natural: [b][och][pos]
#pragma unroll
        for (int r = 0; r < 4; ++r)
            vt[((size_t)b * CH + w * 16 + g * 4 + r) * L + pos] = f2bf(accv[r] + bv4[r]);
    }
}

// ---------------------------------------------------------------------------
// Kernel 2: windowed attention, all-MFMA.  grid 2048 (i = n*8 + b), block 256.
// q from scrambled (bqi=i>>8, nqi=i&255).
// LDS (64KB): qs [64l][64c], ks2 [128j][64c], vs [64c][128j],
//             ps [64l][128j], aos [64l][64c] — all bf16, quad^(row&7) swizzle.
// ---------------------------------------------------------------------------
__global__ __launch_bounds__(256) void attn_mfma(
    const unsigned short* __restrict__ qt, const unsigned short* __restrict__ kt,
    const unsigned short* __restrict__ vt, const float* __restrict__ mask,
    const float* __restrict__ Wo, const float* __restrict__ bo,
    float* __restrict__ outp)
{
    __shared__ unsigned short qs [64 * 64];
    __shared__ unsigned short ks2[128 * 64];
    __shared__ unsigned short vs [64 * 128];
    __shared__ unsigned short ps [64 * 128];
    __shared__ unsigned short aos[64 * 64];

    const int i   = blockIdx.x;
    const int b   = i & 7;
    const int n   = i >> 3;
    const int bqi = i >> 8;
    const int nqi = i & 255;
    const int t    = threadIdx.x;
    const int lane = t & 63;
    const int w    = t >> 6;
    const int g    = lane >> 4;
    const int l15  = lane & 15;
    const int jbase = n * 64 - 64;

    // ---- stage q (64 rows x 128B) ----
    {
        const char* src = (const char*)(qt + ((size_t)bqi * L + nqi * 64) * 64);
#pragma unroll
        for (int it = 0; it < 2; ++it) {
            const int row = (t >> 3) + it * 32, ch = t & 7;
            uint4 d = *(const uint4*)(src + row * 128 + ch * 16);
            *(uint4*)((char*)qs + row * 128 + ((ch ^ (row & 7)) << 4)) = d;
        }
    }
    // ---- stage k window (128 rows x 128B), zero pad rows for n==0 ----
    {
#pragma unroll
        for (int it = 0; it < 4; ++it) {
            const int row = (t >> 3) + it * 32, ch = t & 7;
            uint4 d = make_uint4(0u, 0u, 0u, 0u);
            if (!(n == 0 && row < 64))
                d = *(const uint4*)((const char*)(kt + ((size_t)b * L + jbase + row) * 64) + ch * 16);
            *(uint4*)((char*)ks2 + row * 128 + ((ch ^ (row & 7)) << 4)) = d;
        }
    }
    // ---- stage v window (64 rows x 256B), zero first-half cols for n==0 ----
    {
#pragma unroll
        for (int it = 0; it < 4; ++it) {
            const int row = (t >> 4) + it * 16, ch = t & 15;
            uint4 d = make_uint4(0u, 0u, 0u, 0u);
            if (!(n == 0 && ch < 8))
                d = *(const uint4*)((const char*)(vt + ((size_t)b * CH + row) * L + jbase) + ch * 16);
            *(uint4*)((char*)vs + row * 256 + ((ch ^ (row & 7)) << 4)) = d;
        }
    }
    __syncthreads();

    // ---- E = q^T k : per wave l-strip w*16..+15, all 128 j ----
    f32x4 ae[8];
#pragma unroll
    for (int jt = 0; jt < 8; ++jt) ae[jt] = (f32x4){0.f, 0.f, 0.f, 0.f};
    bf16x8 qa[2];
#pragma unroll
    for (int ks = 0; ks < 2; ++ks) {
        const int row = w * 16 + l15;
        qa[ks] = *(const bf16x8*)((char*)qs + row * 128 + (((ks * 4 + g) ^ (row & 7)) << 4));
    }
#pragma unroll
    for (int jt = 0; jt < 8; ++jt) {
#pragma unroll
        for (int ks = 0; ks < 2; ++ks) {
            const int row = jt * 16 + l15;
            const bf16x8 kb = *(const bf16x8*)((char*)ks2 + row * 128 + (((ks * 4 + g) ^ (row & 7)) << 4));
            ae[jt] = mfma16(qa[ks], kb, ae[jt]);
        }
    }

    // ---- softmax: e = E/8 + log(fm+1e-6); row = (w*16 + 4g + r), col j ----
    const float* mrow = mask + (size_t)b * L + jbase;
    float pw8[8];
#pragma unroll
    for (int jt = 0; jt < 8; ++jt) {
        const int j = l15 + jt * 16;
        pw8[jt] = (n == 0 && j < 64) ? 0.f : mrow[j];
    }
    const int ii0 = w * 16 + g * 4;   // query index base (+r)
#pragma unroll
    for (int jt = 0; jt < 8; ++jt) {
        const int j = l15 + jt * 16;
#pragma unroll
        for (int r = 0; r < 4; ++r) {
            const float fm = (j >= ii0 + r && j < ii0 + r + 64) ? pw8[jt] : 0.f;
            ae[jt][r] = ae[jt][r] * 0.125f + __logf(fm + 1e-6f);
        }
    }
    f32x4 mx, inv;
#pragma unroll
    for (int r = 0; r < 4; ++r) {
        float m = ae[0][r];
#pragma unroll
        for (int jt = 1; jt < 8; ++jt) m = fmaxf(m, ae[jt][r]);
        m = fmaxf(m, __shfl_xor(m, 1));
        m = fmaxf(m, __shfl_xor(m, 2));
        m = fmaxf(m, __shfl_xor(m, 4));
        m = fmaxf(m, __shfl_xor(m, 8));
        mx[r] = m;
    }
    f32x4 sum = {0.f, 0.f, 0.f, 0.f};
#pragma unroll
    for (int jt = 0; jt < 8; ++jt)
#pragma unroll
        for (int r = 0; r < 4; ++r) {
            const float p = __expf(ae[jt][r] - mx[r]);
            ae[jt][r] = p;
            sum[r] += p;
        }
#pragma unroll
    for (int r = 0; r < 4; ++r) {
        float s = sum[r];
        s += __shfl_xor(s, 1);
        s += __shfl_xor(s, 2);
        s += __shfl_xor(s, 4);
        s += __shfl_xor(s, 8);
        inv[r] = 1.0f / s;
    }
    // write att bf16 -> ps[l][j]
#pragma unroll
    for (int jt = 0; jt < 8; ++jt) {
        const int j = l15 + jt * 16;
#pragma unroll
        for (int r = 0; r < 4; ++r) {
            const float fm = (j >= ii0 + r && j < ii0 + r + 64) ? pw8[jt] : 0.f;
            const float p = ae[jt][r] * inv[r] * fm;
            const int lrow = w * 16 + g * 4 + r;
            *(unsigned short*)((char*)ps + lrow * 256 +
                (((j >> 3) ^ (lrow & 7)) << 4) + (j & 7) * 2) = f2bf(p);
        }
    }

    // ---- AO^T[l][c] = att[l][:] x v[c][:] ----
    f32x4 ao[4];
#pragma unroll
    for (int ct = 0; ct < 4; ++ct) ao[ct] = (f32x4){0.f, 0.f, 0.f, 0.f};
#pragma unroll
    for (int ks = 0; ks < 4; ++ks) {
        const int arow = w * 16 + l15;
        const int aq_ = ks * 4 + g;
        const bf16x8 pa = *(const bf16x8*)((char*)ps + arow * 256 + ((aq_ ^ (arow & 7)) << 4));
#pragma unroll
        for (int ct = 0; ct < 4; ++ct) {
            const int vrow = ct * 16 + l15;
            const bf16x8 vb = *(const bf16x8*)((char*)vs + vrow * 256 + ((aq_ ^ (vrow & 7)) << 4));
            ao[ct] = mfma16(pa, vb, ao[ct]);
        }
    }
    // relu -> aos[l][c] bf16
#pragma unroll
    for (int ct = 0; ct < 4; ++ct)
#pragma unroll
        for (int r = 0; r < 4; ++r) {
            const int lr = w * 16 + g * 4 + r;
            const int c  = ct * 16 + l15;
            *(unsigned short*)((char*)aos + lr * 128 +
                (((c >> 3) ^ (lr & 7)) << 4) + (c & 7) * 2) = f2bf(fmaxf(ao[ct][r], 0.f));
        }
    __syncthreads();

    // ---- out = Wo @ relu(AO) + bo, * mask ----
    f32x4 mvv;
#pragma unroll
    for (int lt = 0; lt < 4; ++lt)
        mvv[lt] = mask[(size_t)b * L + n * 64 + lt * 16 + l15];

    bf16x8 bbs[8];   // B fragments: [ks*4+lt]
#pragma unroll
    for (int ks = 0; ks < 2; ++ks)
#pragma unroll
        for (int lt = 0; lt < 4; ++lt) {
            const int brow = lt * 16 + l15;
            bbs[ks * 4 + lt] = *(const bf16x8*)((char*)aos + brow * 128 +
                (((ks * 4 + g) ^ (brow & 7)) << 4));
        }

#pragma unroll 1
    for (int ot = 0; ot < 4; ++ot) {
        const int orow = ot * 64 + w * 16 + l15;
        bf16x8 wa[2];
#pragma unroll
        for (int ks = 0; ks < 2; ++ks)
            wa[ks] = pack8(Wo + (size_t)orow * 64 + ks * 32 + g * 8);
        f32x4 acw[4];
#pragma unroll
        for (int lt = 0; lt < 4; ++lt) acw[lt] = (f32x4){0.f, 0.f, 0.f, 0.f};
#pragma unroll
        for (int ks = 0; ks < 2; ++ks)
#pragma unroll
            for (int lt = 0; lt < 4; ++lt)
                acw[lt] = mfma16(wa[ks], bbs[ks * 4 + lt], acw[lt]);
        const f32x4 bo4 = *(const f32x4*)(bo + ot * 64 + w * 16 + g * 4);
#pragma unroll
        for (int lt = 0; lt < 4; ++lt) {
            const int pos = n * 64 + lt * 16 + l15;
#pragma unroll
            for (int r = 0; r < 4; ++r) {
                const int o = ot * 64 + w * 16 + g * 4 + r;
                outp[((size_t)b * C + o) * L + pos] = (acw[lt][r] + bo4[r]) * mvv[lt];
            }
        }
    }
}

// ---------------------------------------------------------------------------
extern "C" void kernel_launch(void* const* d_in, const int* in_sizes, int n_in,
                              void* d_out, int out_size, void* d_ws, size_t ws_size,
                              hipStream_t stream) {
    const float* x1   = (const float*)d_in[0];
    const float* x2   = (const float*)d_in[1];
    const float* mask = (const float*)d_in[2];
    const float* Wq   = (const float*)d_in[3];
    const float* bq   = (const float*)d_in[4];
    const float* Wk   = (const float*)d_in[5];
    const float* bk   = (const float*)d_in[6];
    const float* Wv   = (const float*)d_in[7];
    const float* bv   = (const float*)d_in[8];
    const float* Wo   = (const float*)d_in[9];
    const float* bo   = (const float*)d_in[10];
    float* out = (float*)d_out;

    unsigned short* qt = (unsigned short*)d_ws;
    unsigned short* kt = qt + (size_t)B * L * CH;
    unsigned short* vt = kt + (size_t)B * L * CH;
    const size_t need = 3ull * B * L * CH * sizeof(unsigned short);
    if (ws_size < need) {
        hipMemsetAsync(d_out, 0, (size_t)out_size * sizeof(float), stream);
        return;
    }

    qkv_mfma<<<dim3(L / 64, B), 256, 0, stream>>>(
        x1, x2, Wq, bq, Wk, bk, Wv, bv, qt, kt, vt);

    attn_mfma<<<dim3(NB * B), 256, 0, stream>>>(
        qt, kt, vt, mask, Wo, bo, out);
}

// Round 4
// 174.843 us; speedup vs baseline: 17.8853x; 1.0022x over previous
//
#include <hip/hip_runtime.h>
#include <math.h>

constexpr int B  = 8;
constexpr int C  = 256;
constexpr int L  = 16384;
constexpr int CH = 64;    // c = C/4
constexpr int NB = 256;   // L / BL

typedef __attribute__((ext_vector_type(8))) short bf16x8;
typedef __attribute__((ext_vector_type(4))) float f32x4;

__device__ __forceinline__ unsigned short f2bf(float f) {
    unsigned u = __builtin_bit_cast(unsigned, f);
    u += 0x7fffu + ((u >> 16) & 1u);          // round-to-nearest-even
    return (unsigned short)(u >> 16);
}

__device__ __forceinline__ f32x4 mfma16(bf16x8 a, bf16x8 b, f32x4 c) {
    return __builtin_amdgcn_mfma_f32_16x16x32_bf16(a, b, c, 0, 0, 0);
}

__device__ __forceinline__ bf16x8 pack8(const float* __restrict__ p) {
    float4 f0 = *(const float4*)p;
    float4 f1 = *(const float4*)(p + 4);
    bf16x8 r;
    r[0] = (short)f2bf(f0.x); r[1] = (short)f2bf(f0.y);
    r[2] = (short)f2bf(f0.z); r[3] = (short)f2bf(f0.w);
    r[4] = (short)f2bf(f1.x); r[5] = (short)f2bf(f1.y);
    r[6] = (short)f2bf(f1.z); r[7] = (short)f2bf(f1.w);
    return r;
}

// ---------------------------------------------------------------------------
// Kernel 1: q/k/v projections via MFMA.  grid (L/64, B), block 256 (4 waves).
// A = W stripe (wave w: och w*16..w*16+15), held as register fragments.
// B = x tile staged in LDS as [pos][c] bf16, quad^(pos&7) swizzled.
// Outputs: q,k transposed [b][pos][och] bf16;  v natural [b][och][pos] bf16.
// ---------------------------------------------------------------------------
__global__ __launch_bounds__(256) void qkv_mfma(
    const float* __restrict__ x1, const float* __restrict__ x2,
    const float* __restrict__ Wq, const float* __restrict__ bq,
    const float* __restrict__ Wk, const float* __restrict__ bk,
    const float* __restrict__ Wv, const float* __restrict__ bv,
    unsigned short* __restrict__ qt, unsigned short* __restrict__ kt,
    unsigned short* __restrict__ vt)
{
    __shared__ unsigned short xs[2][64 * 256];   // 2 x 32KB, [pos][c] swizzled
    const int t    = threadIdx.x;
    const int b    = blockIdx.y;
    const int pos0 = blockIdx.x * 64;
    const int lane = t & 63;
    const int w    = t >> 6;
    const int g    = lane >> 4;
    const int l15  = lane & 15;

    // ---- A fragments (W rows) + biases ----
    const int arow = w * 16 + l15;
    bf16x8 aq[8], ak[8], av[8];
#pragma unroll
    for (int s = 0; s < 8; ++s) {
        const int cb = s * 32 + g * 8;
        aq[s] = pack8(Wq + arow * 256 + cb);
        ak[s] = pack8(Wk + arow * 256 + cb);
        av[s] = pack8(Wv + arow * 256 + cb);
    }
    const f32x4 bq4 = *(const f32x4*)(bq + w * 16 + g * 4);
    const f32x4 bk4 = *(const f32x4*)(bk + w * 16 + g * 4);
    const f32x4 bv4 = *(const f32x4*)(bv + w * 16 + g * 4);

    // ---- stage x1, x2: fp32 [c][pos] -> bf16 LDS [pos][c] swizzled ----
    {
        const int p2  = (t & 31) * 2;   // pos pair
        const int cp0 = t >> 5;         // c-pair 0..7 (+8/iter)
#pragma unroll
        for (int xi = 0; xi < 2; ++xi) {
            const float* xb = (xi ? x2 : x1) + (size_t)b * C * L + pos0;
            char* dst = (char*)xs[xi];
#pragma unroll
            for (int it = 0; it < 16; ++it) {
                const int cp = cp0 + it * 8;
                const int c0 = cp * 2;
                const float2 fa = *(const float2*)(xb + (size_t)c0 * L + p2);
                const float2 fb = *(const float2*)(xb + (size_t)(c0 + 1) * L + p2);
                const unsigned w0 = (unsigned)f2bf(fa.x) | ((unsigned)f2bf(fb.x) << 16);
                const unsigned w1 = (unsigned)f2bf(fa.y) | ((unsigned)f2bf(fb.y) << 16);
                const int quad = cp >> 2, inner = (cp & 3) * 4;
                *(unsigned*)(dst + p2 * 512 + ((quad ^ (p2 & 7)) << 4) + inner) = w0;
                *(unsigned*)(dst + (p2 + 1) * 512 + ((quad ^ ((p2 + 1) & 7)) << 4) + inner) = w1;
            }
        }
    }
    __syncthreads();

    // ---- MFMA over 4 pos sub-tiles ----
#pragma unroll 1
    for (int nt = 0; nt < 4; ++nt) {
        f32x4 accq = {0.f, 0.f, 0.f, 0.f}, acck = accq, accv = accq;
        const int prow = nt * 16 + l15;
        const int rswz = prow & 7;
#pragma unroll
        for (int s = 0; s < 8; ++s) {
            const int byo = prow * 512 + (((s * 4 + g) ^ rswz) << 4);
            const bf16x8 bx1 = *(const bf16x8*)((char*)xs[0] + byo);
            const bf16x8 bx2 = *(const bf16x8*)((char*)xs[1] + byo);
            accq = mfma16(aq[s], bx1, accq);
            acck = mfma16(ak[s], bx1, acck);
            accv = mfma16(av[s], bx2, accv);
        }
        const int pos = pos0 + nt * 16 + l15;
        // q, k transposed: [b][pos][och], 4 consecutive och per lane -> 8B store
        {
            uint2 val;
            val.x = (unsigned)f2bf(accq[0] + bq4[0]) | ((unsigned)f2bf(accq[1] + bq4[1]) << 16);
            val.y = (unsigned)f2bf(accq[2] + bq4[2]) | ((unsigned)f2bf(accq[3] + bq4[3]) << 16);
            *(uint2*)(qt + ((size_t)b * L + pos) * 64 + w * 16 + g * 4) = val;
        }
        {
            uint2 val;
            val.x = (unsigned)f2bf(acck[0] + bk4[0]) | ((unsigned)f2bf(acck[1] + bk4[1]) << 16);
            val.y = (unsigned)f2bf(acck[2] + bk4[2]) | ((unsigned)f2bf(acck[3] + bk4[3]) << 16);
            *(uint2*)(kt + ((size_t)b * L + pos) * 64 + w * 16 + g * 4) = val;
        }
        // v natural: [b][och][pos]
#pragma unroll
        for (int r = 0; r < 4; ++r)
            vt[((size_t)b * CH + w * 16 + g * 4 + r) * L + pos] = f2bf(accv[r] + bv4[r]);
    }
}

// ---------------------------------------------------------------------------
// Kernel 2: windowed attention, all-MFMA.  grid 2048 (i = n*8 + b), block 256.
// q from scrambled (bqi=i>>8, nqi=i&255).
// LDS (64KB): qs [64l][64c], ks2 [128j][64c], vs [64c][128j],
//             ps [64l][128j], aos [64l][64c] — all bf16, quad^(row&7) swizzle.
// ---------------------------------------------------------------------------
__global__ __launch_bounds__(256) void attn_mfma(
    const unsigned short* __restrict__ qt, const unsigned short* __restrict__ kt,
    const unsigned short* __restrict__ vt, const float* __restrict__ mask,
    const float* __restrict__ Wo, const float* __restrict__ bo,
    float* __restrict__ outp)
{
    __shared__ unsigned short qs [64 * 64];
    __shared__ unsigned short ks2[128 * 64];
    __shared__ unsigned short vs [64 * 128];
    __shared__ unsigned short ps [64 * 128];
    __shared__ unsigned short aos[64 * 64];

    const int i   = blockIdx.x;
    const int b   = i & 7;
    const int n   = i >> 3;
    const int bqi = i >> 8;
    const int nqi = i & 255;
    const int t    = threadIdx.x;
    const int lane = t & 63;
    const int w    = t >> 6;
    const int g    = lane >> 4;
    const int l15  = lane & 15;
    const int jbase = n * 64 - 64;

    // ---- stage q (64 rows x 128B) ----
    {
        const char* src = (const char*)(qt + ((size_t)bqi * L + nqi * 64) * 64);
#pragma unroll
        for (int it = 0; it < 2; ++it) {
            const int row = (t >> 3) + it * 32, ch = t & 7;
            uint4 d = *(const uint4*)(src + row * 128 + ch * 16);
            *(uint4*)((char*)qs + row * 128 + ((ch ^ (row & 7)) << 4)) = d;
        }
    }
    // ---- stage k window (128 rows x 128B), zero pad rows for n==0 ----
    {
#pragma unroll
        for (int it = 0; it < 4; ++it) {
            const int row = (t >> 3) + it * 32, ch = t & 7;
            uint4 d = make_uint4(0u, 0u, 0u, 0u);
            if (!(n == 0 && row < 64))
                d = *(const uint4*)((const char*)(kt + ((size_t)b * L + jbase + row) * 64) + ch * 16);
            *(uint4*)((char*)ks2 + row * 128 + ((ch ^ (row & 7)) << 4)) = d;
        }
    }
    // ---- stage v window (64 rows x 256B), zero first-half cols for n==0 ----
    {
#pragma unroll
        for (int it = 0; it < 4; ++it) {
            const int row = (t >> 4) + it * 16, ch = t & 15;
            uint4 d = make_uint4(0u, 0u, 0u, 0u);
            if (!(n == 0 && ch < 8))
                d = *(const uint4*)((const char*)(vt + ((size_t)b * CH + row) * L + jbase) + ch * 16);
            *(uint4*)((char*)vs + row * 256 + ((ch ^ (row & 7)) << 4)) = d;
        }
    }
    __syncthreads();

    // ---- E = q^T k : per wave l-strip w*16..+15, all 128 j ----
    f32x4 ae[8];
#pragma unroll
    for (int jt = 0; jt < 8; ++jt) ae[jt] = (f32x4){0.f, 0.f, 0.f, 0.f};
    bf16x8 qa[2];
#pragma unroll
    for (int ks = 0; ks < 2; ++ks) {
        const int row = w * 16 + l15;
        qa[ks] = *(const bf16x8*)((char*)qs + row * 128 + (((ks * 4 + g) ^ (row & 7)) << 4));
    }
#pragma unroll
    for (int jt = 0; jt < 8; ++jt) {
#pragma unroll
        for (int ks = 0; ks < 2; ++ks) {
            const int row = jt * 16 + l15;
            const bf16x8 kb = *(const bf16x8*)((char*)ks2 + row * 128 + (((ks * 4 + g) ^ (row & 7)) << 4));
            ae[jt] = mfma16(qa[ks], kb, ae[jt]);
        }
    }

    // ---- softmax: e = E/8 + log(fm+1e-6); row = (w*16 + 4g + r), col j ----
    const float* mrow = mask + (size_t)b * L + jbase;
    float pw8[8];
#pragma unroll
    for (int jt = 0; jt < 8; ++jt) {
        const int j = l15 + jt * 16;
        pw8[jt] = (n == 0 && j < 64) ? 0.f : mrow[j];
    }
    const int ii0 = w * 16 + g * 4;   // query index base (+r)
#pragma unroll
    for (int jt = 0; jt < 8; ++jt) {
        const int j = l15 + jt * 16;
#pragma unroll
        for (int r = 0; r < 4; ++r) {
            const float fm = (j >= ii0 + r && j < ii0 + r + 64) ? pw8[jt] : 0.f;
            ae[jt][r] = ae[jt][r] * 0.125f + __logf(fm + 1e-6f);
        }
    }
    f32x4 mx, inv;
#pragma unroll
    for (int r = 0; r < 4; ++r) {
        float m = ae[0][r];
#pragma unroll
        for (int jt = 1; jt < 8; ++jt) m = fmaxf(m, ae[jt][r]);
        m = fmaxf(m, __shfl_xor(m, 1));
        m = fmaxf(m, __shfl_xor(m, 2));
        m = fmaxf(m, __shfl_xor(m, 4));
        m = fmaxf(m, __shfl_xor(m, 8));
        mx[r] = m;
    }
    f32x4 sum = {0.f, 0.f, 0.f, 0.f};
#pragma unroll
    for (int jt = 0; jt < 8; ++jt)
#pragma unroll
        for (int r = 0; r < 4; ++r) {
            const float p = __expf(ae[jt][r] - mx[r]);
            ae[jt][r] = p;
            sum[r] += p;
        }
#pragma unroll
    for (int r = 0; r < 4; ++r) {
        float s = sum[r];
        s += __shfl_xor(s, 1);
        s += __shfl_xor(s, 2);
        s += __shfl_xor(s, 4);
        s += __shfl_xor(s, 8);
        inv[r] = 1.0f / s;
    }
    // write att bf16 -> ps[l][j]
#pragma unroll
    for (int jt = 0; jt < 8; ++jt) {
        const int j = l15 + jt * 16;
#pragma unroll
        for (int r = 0; r < 4; ++r) {
            const float fm = (j >= ii0 + r && j < ii0 + r + 64) ? pw8[jt] : 0.f;
            const float p = ae[jt][r] * inv[r] * fm;
            const int lrow = w * 16 + g * 4 + r;
            *(unsigned short*)((char*)ps + lrow * 256 +
                (((j >> 3) ^ (lrow & 7)) << 4) + (j & 7) * 2) = f2bf(p);
        }
    }

    // ---- AO^T[l][c] = att[l][:] x v[c][:] ----
    f32x4 ao[4];
#pragma unroll
    for (int ct = 0; ct < 4; ++ct) ao[ct] = (f32x4){0.f, 0.f, 0.f, 0.f};
#pragma unroll
    for (int ks = 0; ks < 4; ++ks) {
        const int arow = w * 16 + l15;
        const int aq_ = ks * 4 + g;
        const bf16x8 pa = *(const bf16x8*)((char*)ps + arow * 256 + ((aq_ ^ (arow & 7)) << 4));
#pragma unroll
        for (int ct = 0; ct < 4; ++ct) {
            const int vrow = ct * 16 + l15;
            const bf16x8 vb = *(const bf16x8*)((char*)vs + vrow * 256 + ((aq_ ^ (vrow & 7)) << 4));
            ao[ct] = mfma16(pa, vb, ao[ct]);
        }
    }
    // relu -> aos[l][c] bf16
#pragma unroll
    for (int ct = 0; ct < 4; ++ct)
#pragma unroll
        for (int r = 0; r < 4; ++r) {
            const int lr = w * 16 + g * 4 + r;
            const int c  = ct * 16 + l15;
            *(unsigned short*)((char*)aos + lr * 128 +
                (((c >> 3) ^ (lr & 7)) << 4) + (c & 7) * 2) = f2bf(fmaxf(ao[ct][r], 0.f));
        }
    __syncthreads();

    // ---- out = Wo @ relu(AO) + bo, * mask ----
    f32x4 mvv;
#pragma unroll
    for (int lt = 0; lt < 4; ++lt)
        mvv[lt] = mask[(size_t)b * L + n * 64 + lt * 16 + l15];

    bf16x8 bbs[8];   // B fragments: [ks*4+lt]
#pragma unroll
    for (int ks = 0; ks < 2; ++ks)
#pragma unroll
        for (int lt = 0; lt < 4; ++lt) {
            const int brow = lt * 16 + l15;
            bbs[ks * 4 + lt] = *(const bf16x8*)((char*)aos + brow * 128 +
                (((ks * 4 + g) ^ (brow & 7)) << 4));
        }

#pragma unroll 1
    for (int ot = 0; ot < 4; ++ot) {
        const int orow = ot * 64 + w * 16 + l15;
        bf16x8 wa[2];
#pragma unroll
        for (int ks = 0; ks < 2; ++ks)
            wa[ks] = pack8(Wo + (size_t)orow * 64 + ks * 32 + g * 8);
        f32x4 acw[4];
#pragma unroll
        for (int lt = 0; lt < 4; ++lt) acw[lt] = (f32x4){0.f, 0.f, 0.f, 0.f};
#pragma unroll
        for (int ks = 0; ks < 2; ++ks)
#pragma unroll
            for (int lt = 0; lt < 4; ++lt)
                acw[lt] = mfma16(wa[ks], bbs[ks * 4 + lt], acw[lt]);
        const f32x4 bo4 = *(const f32x4*)(bo + ot * 64 + w * 16 + g * 4);
#pragma unroll
        for (int lt = 0; lt < 4; ++lt) {
            const int pos = n * 64 + lt * 16 + l15;
#pragma unroll
            for (int r = 0; r < 4; ++r) {
                const int o = ot * 64 + w * 16 + g * 4 + r;
                outp[((size_t)b * C + o) * L + pos] = (acw[lt][r] + bo4[r]) * mvv[lt];
            }
        }
    }
}

// ---------------------------------------------------------------------------
extern "C" void kernel_launch(void* const* d_in, const int* in_sizes, int n_in,
                              void* d_out, int out_size, void* d_ws, size_t ws_size,
                              hipStream_t stream) {
    const float* x1   = (const float*)d_in[0];
    const float* x2   = (const float*)d_in[1];
    const float* mask = (const float*)d_in[2];
    const float* Wq   = (const float*)d_in[3];
    const float* bq   = (const float*)d_in[4];
    const float* Wk   = (const float*)d_in[5];
    const float* bk   = (const float*)d_in[6];
    const float* Wv   = (const float*)d_in[7];
    const float* bv   = (const float*)d_in[8];
    const float* Wo   = (const float*)d_in[9];
    const float* bo   = (const float*)d_in[10];
    float* out = (float*)d_out;

    unsigned short* qt = (unsigned short*)d_ws;
    unsigned short* kt = qt + (size_t)B * L * CH;
    unsigned short* vt = kt + (size_t)B * L * CH;
    const size_t need = 3ull * B * L * CH * sizeof(unsigned short);
    if (ws_size < need) {
        hipMemsetAsync(d_out, 0, (size_t)out_size * sizeof(float), stream);
        return;
    }

    qkv_mfma<<<dim3(L / 64, B), 256, 0, stream>>>(
        x1, x2, Wq, bq, Wk, bk, Wv, bv, qt, kt, vt);

    attn_mfma<<<dim3(NB * B), 256, 0, stream>>>(
        qt, kt, vt, mask, Wo, bo, out);
}